// Round 1
// baseline (239.828 us; speedup 1.0000x reference)
//
#include <hip/hip_runtime.h>

#define EPSF 1e-10f
#define SFN 4
#define KPN 32
#define HH 96
#define WW 96
#define NPIX (HH*WW)     // 9216
#define CH 3
#define SH 128
#define SW 128
#define NIMG 64

__device__ inline float wred_sum(float v){
  #pragma unroll
  for(int off=32; off; off>>=1) v += __shfl_xor(v, off, 64);
  return v;
}
__device__ inline float wred_max(float v){
  #pragma unroll
  for(int off=32; off; off>>=1) v = fmaxf(v, __shfl_xor(v, off, 64));
  return v;
}

// ---------------- resize: jax.image.resize bilinear, antialias=True, 128->96 ----------------
__global__ __launch_bounds__(256) void k_resize(const float* __restrict__ img, float* __restrict__ out){
  int idx = blockIdx.x*256 + threadIdx.x;  // over 64*3*96*96
  if (idx >= NIMG*CH*NPIX) return;
  int ox = idx % WW;
  int oy = (idx / WW) % HH;
  int nc = idx / NPIX;   // n*3+c
  float xs = (ox + 0.5f)*(4.0f/3.0f) - 0.5f;
  float ys = (oy + 0.5f)*(4.0f/3.0f) - 0.5f;
  int jx0 = (int)ceilf(xs - 4.0f/3.0f);
  int jy0 = (int)ceilf(ys - 4.0f/3.0f);
  float wx[3], wy[3]; float sx=0.f, sy=0.f;
  #pragma unroll
  for(int t=0;t<3;t++){
    int j = jx0+t;
    float w = 1.0f - 0.75f*fabsf((float)j - xs);
    w = (j>=0 && j<SW) ? fmaxf(w,0.0f) : 0.0f;
    wx[t]=w; sx+=w;
    j = jy0+t;
    w = 1.0f - 0.75f*fabsf((float)j - ys);
    w = (j>=0 && j<SH) ? fmaxf(w,0.0f) : 0.0f;
    wy[t]=w; sy+=w;
  }
  float inv = 1.0f/(sx*sy);
  const float* base = img + (size_t)nc*SH*SW;
  float acc=0.f;
  #pragma unroll
  for(int ty=0;ty<3;ty++){
    if (wy[ty]==0.f) continue;
    int jy = min(max(jy0+ty,0), SH-1);
    #pragma unroll
    for(int tx=0;tx<3;tx++){
      if (wx[tx]==0.f) continue;
      int jx = min(max(jx0+tx,0), SW-1);
      acc += wy[ty]*wx[tx]*base[jy*SW+jx];
    }
  }
  out[idx] = acc*inv;
}

// ---------------- local entropy ----------------
// Per block: one n, one 16-row stripe, loop c and bins.
// ent(pixel) = mean_c [ log(S) - T/S ],  S = sum_b p_b, T = sum_b p_b log(p_b+eps)
__global__ __launch_bounds__(256) void k_entropy(const float* __restrict__ rimg, float* __restrict__ ent){
  __shared__ float img[18][96];
  __shared__ float kt[18][98];   // col+1 indexing, [0] and [97] are zero pads
  __shared__ float rs[18][96];
  int tid = threadIdx.x;
  int n = blockIdx.y;            // 0..63
  int r0 = blockIdx.x * 16;      // stripe base output row
  float entacc[6];
  #pragma unroll
  for(int j=0;j<6;j++) entacc[j]=0.f;
  if (tid < 18){ kt[tid][0]=0.f; kt[tid][97]=0.f; }
  for (int c=0;c<CH;c++){
    const float* src = rimg + ((size_t)(n*CH+c))*NPIX;
    __syncthreads();
    for (int idx=tid; idx<18*96; idx+=256){
      int lr = idx/96, col = idx%96;
      int gr = r0 - 1 + lr;
      img[lr][col] = (gr>=0 && gr<HH) ? src[gr*96+col] : 0.f;
    }
    __syncthreads();
    float S[6], T[6];
    #pragma unroll
    for(int j=0;j<6;j++){S[j]=0.f;T[j]=0.f;}
    for (int b=0;b<16;b++){
      float cb = (float)b * (1.0f/15.0f);
      for (int idx=tid; idx<18*96; idx+=256){
        int lr = idx/96, col = idx%96;
        int gr = r0 - 1 + lr;
        float v = img[lr][col] - cb;
        kt[lr][col+1] = (gr>=0 && gr<HH) ? __expf(-50.f*v*v) : 0.f;
      }
      __syncthreads();
      for (int idx=tid; idx<18*96; idx+=256){
        int lr = idx/96, col = idx%96;
        rs[lr][col] = kt[lr][col] + kt[lr][col+1] + kt[lr][col+2];
      }
      __syncthreads();
      #pragma unroll
      for (int j=0;j<6;j++){
        int pix = tid + j*256;
        int orow = pix/96, col = pix%96;
        int lr = orow+1;
        float p = (rs[lr-1][col]+rs[lr][col]+rs[lr+1][col]) * (1.f/9.f);
        S[j] += p;
        T[j] += p * __logf(p + EPSF);
      }
      __syncthreads();
    }
    #pragma unroll
    for (int j=0;j<6;j++){
      float Sp = S[j] + EPSF;
      entacc[j] += __logf(Sp) - T[j]/Sp;
    }
  }
  #pragma unroll
  for (int j=0;j<6;j++){
    int pix = tid + j*256;
    int orow = pix/96, col = pix%96;
    ent[(size_t)n*NPIX + (size_t)(r0+orow)*96 + col] = entacc[j] * (1.f/3.f);
  }
}

// ---------------- main gaussians pass ----------------
// block: (pixel tile of 256, b). Loops kp, all 4 s in registers -> each gaussian read once.
__global__ __launch_bounds__(256) void k_main(const float* __restrict__ gauss,
                                              const float* __restrict__ status,
                                              const float* __restrict__ ent,
                                              float* __restrict__ mi_sum,
                                              float* __restrict__ melN,
                                              float* __restrict__ mcelN,
                                              float* __restrict__ reS,
                                              float* __restrict__ ceS,
                                              unsigned int* __restrict__ gmax){
  __shared__ float part[128][4];
  int tid = threadIdx.x;
  int lane = tid & 63, w = tid >> 6;
  int tile = blockIdx.x;   // 0..35
  int b = blockIdx.y;      // 0..15
  int pix = tile*256 + tid;
  float re[4], se[4], ce[4];
  #pragma unroll
  for (int s=0;s<4;s++) re[s] = ent[(size_t)(b*4+s)*NPIX + pix];
  #pragma unroll
  for (int s=0;s<4;s++){ se[s] = re[(s+3)&3]; ce[s] = fmaxf(re[s], se[s]) - se[s]; }
  float am[4]={0,0,0,0}, ag[4]={0,0,0,0};
  for (int kp=0;kp<32;kp++){
    float ah[4];
    #pragma unroll
    for (int s=0;s<4;s++){
      float g = gauss[((size_t)((b*4+s)*32 + kp))*NPIX + pix];
      float hm = fminf(fmaxf(g - 0.1f, 0.f)*3.5f, 1.f);
      float st = status[(b*4+s)*32 + kp];
      ah[s] = st * hm;
      am[s] += ah[s];
      ag[s] += g;
    }
    #pragma unroll
    for (int s=0;s<4;s++){
      float a = ah[s], sh = ah[(s+3)&3];
      float recon = se[s]*(1.f-a)*(1.f-sh) + re[s]*a + ce[s]*(1.f-a);
      float mi = fminf(recon, re[s]);
      float r = wred_sum(mi);
      if (lane==0) part[s*32+kp][w] = r;
    }
  }
  __syncthreads();
  if (tid < 128){
    float v = part[tid][0]+part[tid][1]+part[tid][2]+part[tid][3];
    int s = tid >> 5, kp = tid & 31;
    atomicAdd(&mi_sum[(b*4+s)*32 + kp], v);
  }
  #pragma unroll
  for (int s=0;s<4;s++){
    float amc = fminf(am[s], 1.f);
    float q = 1.f - amc;
    float r1 = wred_sum(re[s]*q);
    float r2 = wred_sum(ce[s]*q);
    float r3 = wred_sum(re[s]);
    float r4 = wred_sum(ce[s]);
    float r5 = wred_max(ag[s]);
    if (lane==0){
      atomicAdd(&melN[b*4+s], r1);
      atomicAdd(&mcelN[b*4+s], r2);
      atomicAdd(&reS[b*4+s], r3);
      atomicAdd(&ceS[b*4+s], r4);
      atomicMax(&gmax[b*4+s], __float_as_uint(r5));
    }
  }
}

// ---------------- finalization ----------------
__global__ __launch_bounds__(256) void k_final(const float* __restrict__ gauss,
                                               const float* __restrict__ coords,
                                               const float* __restrict__ status,
                                               const float* __restrict__ mi_sum,
                                               const float* __restrict__ melN,
                                               const float* __restrict__ mcelN,
                                               const float* __restrict__ reS,
                                               const float* __restrict__ ceS,
                                               const unsigned int* __restrict__ gmax,
                                               float* __restrict__ out){
  __shared__ float red[256];
  __shared__ float hs_sh;
  int tid = threadIdx.x;
  // heatmap_size = sum over heatmaps[0,0,0]
  float acc = 0.f;
  for (int pix = tid; pix < NPIX; pix += 256){
    float g = gauss[pix];
    acc += fminf(fmaxf(g - 0.1f, 0.f)*3.5f, 1.f);
  }
  red[tid] = acc;
  __syncthreads();
  for (int o=128;o;o>>=1){ if (tid<o) red[tid]+=red[tid+o]; __syncthreads(); }
  if (tid==0) hs_sh = red[0];
  __syncthreads();
  float hs = hs_sh;
  float mint = 0.f;
  if (tid < 64){
    int n = tid;                 // b*4+s
    int s = n & 3;
    int np = (s==0) ? n+3 : n-1; // roll(,1): previous in SF ring
    float mc = 0.f, sl = 0.f;
    for (int kp=0;kp<KPN;kp++){
      float dx = coords[(n*KPN+kp)*2+0] - coords[(np*KPN+kp)*2+0];
      float dy = coords[(n*KPN+kp)*2+1] - coords[(np*KPN+kp)*2+1];
      float d = sqrtf(dx*dx + dy*dy);
      float st = status[n*KPN+kp];
      mc += d * st * status[np*KPN+kp];
      sl += st;
    }
    sl *= (1.f/KPN);
    float rsum = reS[n], csum = ceS[n];
    float mel = melN[n] / (rsum + EPSF);
    float mcel = (s==0) ? 0.f : mcelN[n] / (csum + EPSF);
    float rcs = 0.f;
    for (int kp=0;kp<KPN;kp++) rcs += rsum - mi_sum[n*KPN+kp];
    float rc = rcs * (1.f/KPN) / hs;
    float itl = rc + 0.1f * mc;
    float ovl = fmaxf(__uint_as_float(gmax[n]) - 1.5f, 0.f) * (1.f/KPN);
    mint = 100.f*mel + 100.f*mcel + itl + 10.f*ovl + (1.f-mel)*2.5f*sl;
  }
  red[tid] = mint;
  __syncthreads();
  for (int o=128;o;o>>=1){ if (tid<o) red[tid]+=red[tid+o]; __syncthreads(); }
  if (tid==0) out[0] = red[0] * (1.f/64.f);
}

extern "C" void kernel_launch(void* const* d_in, const int* in_sizes, int n_in,
                              void* d_out, int out_size, void* d_ws, size_t ws_size,
                              hipStream_t stream){
  const float* coords = (const float*)d_in[0];
  const float* gauss  = (const float*)d_in[1];
  const float* status = (const float*)d_in[2];
  const float* images = (const float*)d_in[3];
  float* out = (float*)d_out;
  float* rimg = (float*)d_ws;                         // 64*3*9216 f32
  float* ent  = rimg + (size_t)NIMG*CH*NPIX;          // 64*9216 f32
  float* mi_sum = ent + (size_t)NIMG*NPIX;            // 2048 f32
  float* melN  = mi_sum + 2048;                       // 64
  float* mcelN = melN + 64;
  float* reS   = mcelN + 64;
  float* ceS   = reS + 64;
  unsigned int* gmax = (unsigned int*)(ceS + 64);     // 64
  hipMemsetAsync(mi_sum, 0, (2048 + 5*64)*sizeof(float), stream);
  k_resize<<<(NIMG*CH*NPIX + 255)/256, 256, 0, stream>>>(images, rimg);
  k_entropy<<<dim3(6,64), 256, 0, stream>>>(rimg, ent);
  k_main<<<dim3(36,16), 256, 0, stream>>>(gauss, status, ent, mi_sum, melN, mcelN, reS, ceS, gmax);
  k_final<<<1,256,0,stream>>>(gauss, coords, status, mi_sum, melN, mcelN, reS, ceS, gmax, out);
}

// Round 2
// 117.467 us; speedup vs baseline: 2.0417x; 2.0417x over previous
//
#include <hip/hip_runtime.h>

#define EPSF 1e-10f
#define KPN 32
#define HH 96
#define WW 96
#define NPIX (HH*WW)     // 9216
#define CH 3
#define SH 128
#define SW 128
#define NIMG 64

__device__ inline float wred_sum(float v){
  #pragma unroll
  for(int off=32; off; off>>=1) v += __shfl_xor(v, off, 64);
  return v;
}
__device__ inline float wred_max(float v){
  #pragma unroll
  for(int off=32; off; off>>=1) v = fmaxf(v, __shfl_xor(v, off, 64));
  return v;
}

// ---------------- resize: jax.image.resize bilinear, antialias=True, 128->96 ----------------
__global__ __launch_bounds__(256) void k_resize(const float* __restrict__ img, float* __restrict__ out){
  int idx = blockIdx.x*256 + threadIdx.x;
  if (idx >= NIMG*CH*NPIX) return;
  int ox = idx % WW;
  int oy = (idx / WW) % HH;
  int nc = idx / NPIX;
  float xs = (ox + 0.5f)*(4.0f/3.0f) - 0.5f;
  float ys = (oy + 0.5f)*(4.0f/3.0f) - 0.5f;
  int jx0 = (int)ceilf(xs - 4.0f/3.0f);
  int jy0 = (int)ceilf(ys - 4.0f/3.0f);
  float wx[3], wy[3]; float sx=0.f, sy=0.f;
  #pragma unroll
  for(int t=0;t<3;t++){
    int j = jx0+t;
    float w = 1.0f - 0.75f*fabsf((float)j - xs);
    w = (j>=0 && j<SW) ? fmaxf(w,0.0f) : 0.0f;
    wx[t]=w; sx+=w;
    j = jy0+t;
    w = 1.0f - 0.75f*fabsf((float)j - ys);
    w = (j>=0 && j<SH) ? fmaxf(w,0.0f) : 0.0f;
    wy[t]=w; sy+=w;
  }
  float inv = 1.0f/(sx*sy);
  const float* base = img + (size_t)nc*SH*SW;
  float acc=0.f;
  #pragma unroll
  for(int ty=0;ty<3;ty++){
    if (wy[ty]==0.f) continue;
    int jy = min(max(jy0+ty,0), SH-1);
    #pragma unroll
    for(int tx=0;tx<3;tx++){
      if (wx[tx]==0.f) continue;
      int jx = min(max(jx0+tx,0), SW-1);
      acc += wy[ty]*wx[tx]*base[jy*SW+jx];
    }
  }
  out[idx] = acc*inv;
}

// ---------------- local entropy ----------------
// Thread owns (col, ch); 8-output-row stripe with 10-row halo in registers.
// Incremental bin kernel: k_{b+1} = k_b * stp * rb,  stp = exp(100 v / 15),
// rb = exp(-50/225 * (2b+1)) uniform scalar. LDS only for horizontal 3-tap.
__global__ __launch_bounds__(320) void k_entropy(const float* __restrict__ rimg, float* __restrict__ ent){
  __shared__ float kt[3][10][98];   // col+1 indexing, [0]/[97] zero pads
  int tid = threadIdx.x;
  int n = blockIdx.y;               // 0..63
  int r0 = blockIdx.x * 8;          // stripe base output row
  int col = tid % 96, ch = tid / 96;
  bool act = tid < 288;
  if (tid < 30){ int c = tid/10, r = tid%10; kt[c][r][0] = 0.f; kt[c][r][97] = 0.f; }
  float cur[10], stp[10];
  if (act){
    const float* src = rimg + ((size_t)(n*CH+ch))*NPIX;
    #pragma unroll
    for (int r=0;r<10;r++){
      int gr = r0 - 1 + r;
      if (gr >= 0 && gr < HH){
        float v = src[gr*96+col];
        cur[r] = __expf(-50.f*v*v);
        stp[r] = __expf(6.6666667f*v);
      } else { cur[r]=0.f; stp[r]=1.f; }
    }
  } else {
    #pragma unroll
    for (int r=0;r<10;r++){ cur[r]=0.f; stp[r]=1.f; }
  }
  float S[8], T[8];
  #pragma unroll
  for (int o=0;o<8;o++){ S[o]=0.f; T[o]=0.f; }
  float rb = __expf(-0.22222222f);
  const float r2 = rb*rb;
  for (int b=0;b<16;b++){
    if (act){
      #pragma unroll
      for (int r=0;r<10;r++) kt[ch][r][col+1] = cur[r];
    }
    __syncthreads();
    float rs[10];
    if (act){
      #pragma unroll
      for (int r=0;r<10;r++) rs[r] = kt[ch][r][col] + cur[r] + kt[ch][r][col+2];
    }
    __syncthreads();
    if (act){
      #pragma unroll
      for (int o=0;o<8;o++){
        float p = (rs[o]+rs[o+1]+rs[o+2]) * (1.f/9.f);
        S[o] += p;
        T[o] += p * __logf(p + EPSF);
      }
      float m = rb;
      #pragma unroll
      for (int r=0;r<10;r++) cur[r] *= stp[r]*m;
    }
    rb *= r2;
  }
  // per-channel entropy -> LDS (reuse kt), then mean over channels
  float* ebuf = &kt[0][0][0];       // need 3*8*96 = 2304 <= 2940
  if (act){
    #pragma unroll
    for (int o=0;o<8;o++){
      float Sp = S[o] + EPSF;
      ebuf[(ch*8+o)*96 + col] = __logf(Sp) - T[o]/Sp;
    }
  }
  __syncthreads();
  for (int i = tid; i < 768; i += 320){
    int o = i/96, c = i%96;
    float e = (ebuf[o*96+c] + ebuf[(8+o)*96+c] + ebuf[(16+o)*96+c]) * (1.f/3.f);
    ent[(size_t)n*NPIX + (size_t)(r0+o)*96 + c] = e;
  }
}

// ---------------- main gaussians pass ----------------
// float2 per thread; no in-loop reductions (mi accumulated per-thread, Sum over kp only).
__global__ __launch_bounds__(256) void k_main(const float* __restrict__ gauss,
                                              const float* __restrict__ status,
                                              const float* __restrict__ ent,
                                              float* __restrict__ miS,
                                              float* __restrict__ melN,
                                              float* __restrict__ mcelN,
                                              float* __restrict__ reS,
                                              float* __restrict__ ceS,
                                              unsigned int* __restrict__ gmax){
  __shared__ float st_sh[128];
  int tid = threadIdx.x;
  int lane = tid & 63;
  int tile = blockIdx.x;   // 0..17
  int b = blockIdx.y;      // 0..15
  if (tid < 128) st_sh[tid] = status[b*128 + tid];
  __syncthreads();
  int p2 = tile*256 + tid;                 // float2 index in 4608-wide plane
  const float2* g2 = (const float2*)gauss;
  const float2* e2 = (const float2*)ent;
  float2 re[4], se[4], ce[4];
  #pragma unroll
  for (int s=0;s<4;s++) re[s] = e2[(size_t)(b*4+s)*4608 + p2];
  #pragma unroll
  for (int s=0;s<4;s++){
    se[s] = re[(s+3)&3];
    ce[s].x = fmaxf(re[s].x, se[s].x) - se[s].x;
    ce[s].y = fmaxf(re[s].y, se[s].y) - se[s].y;
  }
  float2 am[4], ag[4], mi[4];
  #pragma unroll
  for (int s=0;s<4;s++){ am[s]=make_float2(0,0); ag[s]=make_float2(0,0); mi[s]=make_float2(0,0); }
  #pragma unroll 4
  for (int kp=0;kp<32;kp++){
    float2 ah[4];
    #pragma unroll
    for (int s=0;s<4;s++){
      float2 g = g2[((size_t)((b*4+s)*32 + kp))*4608 + p2];
      float st = st_sh[s*32+kp];
      float hx = fminf(fmaxf(g.x - 0.1f, 0.f)*3.5f, 1.f);
      float hy = fminf(fmaxf(g.y - 0.1f, 0.f)*3.5f, 1.f);
      ah[s].x = st*hx; ah[s].y = st*hy;
      am[s].x += ah[s].x; am[s].y += ah[s].y;
      ag[s].x += g.x;     ag[s].y += g.y;
    }
    #pragma unroll
    for (int s=0;s<4;s++){
      float2 sh = ah[(s+3)&3];
      float rx = se[s].x*(1.f-ah[s].x)*(1.f-sh.x) + re[s].x*ah[s].x + ce[s].x*(1.f-ah[s].x);
      float ry = se[s].y*(1.f-ah[s].y)*(1.f-sh.y) + re[s].y*ah[s].y + ce[s].y*(1.f-ah[s].y);
      mi[s].x += fminf(rx, re[s].x);
      mi[s].y += fminf(ry, re[s].y);
    }
  }
  #pragma unroll
  for (int s=0;s<4;s++){
    float qx = 1.f - fminf(am[s].x, 1.f);
    float qy = 1.f - fminf(am[s].y, 1.f);
    float r1 = wred_sum(re[s].x*qx + re[s].y*qy);
    float r2 = wred_sum(ce[s].x*qx + ce[s].y*qy);
    float r3 = wred_sum(re[s].x + re[s].y);
    float r4 = wred_sum(ce[s].x + ce[s].y);
    float r5 = wred_max(fmaxf(ag[s].x, ag[s].y));
    float r6 = wred_sum(mi[s].x + mi[s].y);
    if (lane==0){
      atomicAdd(&melN[b*4+s], r1);
      atomicAdd(&mcelN[b*4+s], r2);
      atomicAdd(&reS[b*4+s], r3);
      atomicAdd(&ceS[b*4+s], r4);
      atomicMax(&gmax[b*4+s], __float_as_uint(r5));
      atomicAdd(&miS[b*4+s], r6);
    }
  }
}

// ---------------- finalization ----------------
__global__ __launch_bounds__(256) void k_final(const float* __restrict__ gauss,
                                               const float* __restrict__ coords,
                                               const float* __restrict__ status,
                                               const float* __restrict__ miS,
                                               const float* __restrict__ melN,
                                               const float* __restrict__ mcelN,
                                               const float* __restrict__ reS,
                                               const float* __restrict__ ceS,
                                               const unsigned int* __restrict__ gmax,
                                               float* __restrict__ out){
  __shared__ float red[256];
  __shared__ float hs_sh;
  int tid = threadIdx.x;
  float acc = 0.f;
  for (int pix = tid; pix < NPIX; pix += 256){
    float g = gauss[pix];
    acc += fminf(fmaxf(g - 0.1f, 0.f)*3.5f, 1.f);
  }
  red[tid] = acc;
  __syncthreads();
  for (int o=128;o;o>>=1){ if (tid<o) red[tid]+=red[tid+o]; __syncthreads(); }
  if (tid==0) hs_sh = red[0];
  __syncthreads();
  float hs = hs_sh;
  float mint = 0.f;
  if (tid < 64){
    int n = tid;                 // b*4+s
    int s = n & 3;
    int np = (s==0) ? n+3 : n-1;
    float mc = 0.f, sl = 0.f;
    for (int kp=0;kp<KPN;kp++){
      float dx = coords[(n*KPN+kp)*2+0] - coords[(np*KPN+kp)*2+0];
      float dy = coords[(n*KPN+kp)*2+1] - coords[(np*KPN+kp)*2+1];
      float d = sqrtf(dx*dx + dy*dy);
      float st = status[n*KPN+kp];
      mc += d * st * status[np*KPN+kp];
      sl += st;
    }
    sl *= (1.f/KPN);
    float rsum = reS[n], csum = ceS[n];
    float mel = melN[n] / (rsum + EPSF);
    float mcel = (s==0) ? 0.f : mcelN[n] / (csum + EPSF);
    float rc = (rsum - miS[n]*(1.f/KPN)) / hs;
    float itl = rc + 0.1f * mc;
    float ovl = fmaxf(__uint_as_float(gmax[n]) - 1.5f, 0.f) * (1.f/KPN);
    mint = 100.f*mel + 100.f*mcel + itl + 10.f*ovl + (1.f-mel)*2.5f*sl;
  }
  red[tid] = mint;
  __syncthreads();
  for (int o=128;o;o>>=1){ if (tid<o) red[tid]+=red[tid+o]; __syncthreads(); }
  if (tid==0) out[0] = red[0] * (1.f/64.f);
}

extern "C" void kernel_launch(void* const* d_in, const int* in_sizes, int n_in,
                              void* d_out, int out_size, void* d_ws, size_t ws_size,
                              hipStream_t stream){
  const float* coords = (const float*)d_in[0];
  const float* gauss  = (const float*)d_in[1];
  const float* status = (const float*)d_in[2];
  const float* images = (const float*)d_in[3];
  float* out = (float*)d_out;
  float* rimg = (float*)d_ws;                         // 64*3*9216 f32
  float* ent  = rimg + (size_t)NIMG*CH*NPIX;          // 64*9216 f32
  float* miS  = ent + (size_t)NIMG*NPIX;              // 64
  float* melN = miS + 64;
  float* mcelN = melN + 64;
  float* reS   = mcelN + 64;
  float* ceS   = reS + 64;
  unsigned int* gmax = (unsigned int*)(ceS + 64);     // 64
  hipMemsetAsync(miS, 0, 6*64*sizeof(float), stream);
  k_resize<<<(NIMG*CH*NPIX + 255)/256, 256, 0, stream>>>(images, rimg);
  k_entropy<<<dim3(12,64), 320, 0, stream>>>(rimg, ent);
  k_main<<<dim3(18,16), 256, 0, stream>>>(gauss, status, ent, miS, melN, mcelN, reS, ceS, gmax);
  k_final<<<1,256,0,stream>>>(gauss, coords, status, miS, melN, mcelN, reS, ceS, gmax, out);
}